// Round 2
// baseline (415.999 us; speedup 1.0000x reference)
//
#include <hip/hip_runtime.h>
#include <stdint.h>
#include <math.h>

#define BLOCK 1024
#define NBINS 8192
#define CAND_CAP 2048
#define CAND_MIN 128
#define NEGV -1e30f
#define EPSV 1e-5f
#define NWAVES (BLOCK/64)

__device__ __forceinline__ uint32_t toOrd(float f) {
  uint32_t u = __float_as_uint(f);
  return (u & 0x80000000u) ? ~u : (u | 0x80000000u);
}
__device__ __forceinline__ float fromOrd(uint32_t o) {
  uint32_t u = (o & 0x80000000u) ? (o & 0x7fffffffu) : ~o;
  return __uint_as_float(u);
}

struct SM {
  uint32_t hist[NBINS];
  uint64_t cand[CAND_CAP];
  float redf[NWAVES];
  int   redi[NWAVES];
  int cnt;
  int bstar;
  float m, S, Sx;
  float kth_x, cutoff_x, mpthr;
  float L, token_lp;
  int greedy;
};

__device__ __forceinline__ float candVal(const uint64_t* cand, int i) {
  return fromOrd(~(uint32_t)(cand[i] >> 32));
}

__global__ void __launch_bounds__(BLOCK)
sampler_kernel(const float* __restrict__ logits,
               const float* __restrict__ temp_,
               const float* __restrict__ minp_,
               const float* __restrict__ topp_,
               const int*   __restrict__ topk_,
               const float* __restrict__ noise_,
               float* __restrict__ out,
               int B, int V, int nlp)
{
  __shared__ SM sm;
  const int row = blockIdx.x;
  const int tid = threadIdx.x;
  const int lane = tid & 63;
  const int wv = tid >> 6;
  const float* lrow = logits + (size_t)row * V;
  const float* nrow = noise_ + (size_t)row * V;
  const int V4 = V >> 2;
  const int Vt = V4 << 2;
  const float4* l4 = (const float4*)lrow;
  const float4* n4 = (const float4*)nrow;

  for (int i = tid; i < NBINS; i += BLOCK) sm.hist[i] = 0u;
  if (tid == 0) sm.cnt = 0;
  __syncthreads();

  // ---- scan 1: row max + orderable-float histogram ----
  float lmax = -INFINITY;
  for (int i = tid; i < V4; i += BLOCK) {
    float4 v = l4[i];
    float a[4] = {v.x, v.y, v.z, v.w};
    #pragma unroll
    for (int c = 0; c < 4; c++) {
      lmax = fmaxf(lmax, a[c]);
      atomicAdd(&sm.hist[toOrd(a[c]) >> 19], 1u);
    }
  }
  for (int i = Vt + tid; i < V; i += BLOCK) {
    float a = lrow[i];
    lmax = fmaxf(lmax, a);
    atomicAdd(&sm.hist[toOrd(a) >> 19], 1u);
  }
  #pragma unroll
  for (int o = 32; o; o >>= 1) lmax = fmaxf(lmax, __shfl_down(lmax, o));
  if (lane == 0) sm.redf[wv] = lmax;
  __syncthreads();
  if (tid == 0) {
    float mm = sm.redf[0];
    for (int w = 1; w < NWAVES; w++) mm = fmaxf(mm, sm.redf[w]);
    sm.m = mm;
    uint32_t cum = 0; int b = NBINS - 1;
    for (; b > 0; b--) { cum += sm.hist[b]; if (cum >= CAND_MIN) break; }
    sm.bstar = b;
  }
  __syncthreads();

  const float m = sm.m;
  const int bstar = sm.bstar;
  const float t = temp_[row];
  const float safe_t = (t < EPSV) ? 1.0f : t;
  const float m_x = m / safe_t;

  // ---- scan 2: S (log_softmax denom), Sx (min_p probs denom), collect candidates ----
  float S = 0.f, Sx = 0.f;
  for (int i = tid; i < V4; i += BLOCK) {
    float4 v = l4[i];
    float a[4] = {v.x, v.y, v.z, v.w};
    #pragma unroll
    for (int c = 0; c < 4; c++) {
      S += expf(a[c] - m);
      float x = a[c] / safe_t;
      Sx += expf(x - m_x);
      uint32_t o = toOrd(a[c]);
      if ((int)(o >> 19) >= bstar) {
        int slot = atomicAdd(&sm.cnt, 1);
        if (slot < CAND_CAP)
          sm.cand[slot] = ((uint64_t)(~o) << 32) | (uint32_t)(i * 4 + c);
      }
    }
  }
  for (int i = Vt + tid; i < V; i += BLOCK) {
    float a = lrow[i];
    S += expf(a - m);
    float x = a / safe_t;
    Sx += expf(x - m_x);
    uint32_t o = toOrd(a);
    if ((int)(o >> 19) >= bstar) {
      int slot = atomicAdd(&sm.cnt, 1);
      if (slot < CAND_CAP)
        sm.cand[slot] = ((uint64_t)(~o) << 32) | (uint32_t)i;
    }
  }
  #pragma unroll
  for (int o = 32; o; o >>= 1) { S += __shfl_down(S, o); Sx += __shfl_down(Sx, o); }
  if (lane == 0) sm.redf[wv] = S;
  __syncthreads();
  if (tid == 0) { float s = 0; for (int w = 0; w < NWAVES; w++) s += sm.redf[w]; sm.S = s; }
  __syncthreads();
  if (lane == 0) sm.redf[wv] = Sx;
  __syncthreads();
  if (tid == 0) { float s = 0; for (int w = 0; w < NWAVES; w++) s += sm.redf[w]; sm.Sx = s; }
  __syncthreads();

  const int count = min(sm.cnt, CAND_CAP);
  for (int i = count + tid; i < CAND_CAP; i += BLOCK) sm.cand[i] = ~0ull;
  __syncthreads();

  // ---- bitonic sort ascending on key (~ord<<32 | idx) => value desc, idx asc ----
  for (int ks = 2; ks <= CAND_CAP; ks <<= 1) {
    for (int j = ks >> 1; j > 0; j >>= 1) {
      for (int e = tid; e < CAND_CAP; e += BLOCK) {
        int p = e ^ j;
        if (p > e) {
          uint64_t a = sm.cand[e], b2 = sm.cand[p];
          bool up = ((e & ks) == 0);
          if ((a > b2) == up) { sm.cand[e] = b2; sm.cand[p] = a; }
        }
      }
      __syncthreads();
    }
  }

  // ---- serial per-row cutoff computation (thread 0) ----
  if (tid == 0) {
    const float Sx_ = sm.Sx;
    const float L = logf(sm.S);
    sm.L = L;
    // auto-detect int64 vs int32 storage for top_k (k in [1,99] => never 0)
    int i64mode = (B > 1 && topk_[1] == 0) ? 1 : 0;
    int kraw = i64mode ? topk_[2 * row] : topk_[row];
    int k = kraw < 1 ? 1 : (kraw > V ? V : kraw);
    int keff = k < count ? k : count;
    float tp = 1.0f / Sx_;
    float mpthr = minp_[row] * tp;
    sm.mpthr = mpthr;
    float topp = topp_[row];

    // min_p passing set is a prefix of the sorted candidates
    int np = 0;
    while (np < keff) {
      float xl = candVal(sm.cand, np) / safe_t;
      float p = expf(xl - m_x) / Sx_;
      if (p < mpthr) break;
      np++;
    }
    float kth_x = NEGV;
    if (np == k) kth_x = candVal(sm.cand, k - 1) / safe_t;
    int kk = np;  // min(k, np)

    // top_p over the first kk entries (rest are exp->0)
    float S2 = 0.f;
    for (int i = 0; i < kk; i++) {
      float xl = candVal(sm.cand, i) / safe_t;
      S2 += expf(xl - m_x);
    }
    float cum = 0.f; int nkeep = 0;
    for (int i = 0; i < kk; i++) {
      float xl = candVal(sm.cand, i) / safe_t;
      float sp = expf(xl - m_x) / S2;
      cum += sp;
      if (cum - sp < topp) nkeep++;
    }
    float cutoff_x = NEGV;
    if (!(cum < topp)) {     // cum < topp => nkeep = V => cutoff NEG (no-op)
      if (nkeep < 1) nkeep = 1;
      cutoff_x = candVal(sm.cand, nkeep - 1) / safe_t;
    }
    sm.kth_x = kth_x;
    sm.cutoff_x = cutoff_x;
    sm.greedy = (int)(uint32_t)(sm.cand[0] & 0xffffffffu);
  }
  __syncthreads();

  // ---- scan 3: argmax over kept of x + gumbel (first-index ties) ----
  const float kth_x = sm.kth_x, cutoff_x = sm.cutoff_x, mpthr = sm.mpthr, SxR = sm.Sx;
  float bestv = -INFINITY; int besti = 0;
  for (int i = tid; i < V4; i += BLOCK) {
    float4 lv = l4[i]; float4 uv = n4[i];
    float la[4] = {lv.x, lv.y, lv.z, lv.w};
    float ua[4] = {uv.x, uv.y, uv.z, uv.w};
    #pragma unroll
    for (int c = 0; c < 4; c++) {
      float x = la[c] / safe_t;
      float p = expf(x - m_x) / SxR;
      float val = NEGV;
      if (p >= mpthr && x >= kth_x && x >= cutoff_x)
        val = x + (-logf(-logf(ua[c])));
      if (val > bestv) { bestv = val; besti = i * 4 + c; }
    }
  }
  for (int i = Vt + tid; i < V; i += BLOCK) {
    float x = lrow[i] / safe_t;
    float p = expf(x - m_x) / SxR;
    float val = NEGV;
    if (p >= mpthr && x >= kth_x && x >= cutoff_x)
      val = x + (-logf(-logf(nrow[i])));
    if (val > bestv) { bestv = val; besti = i; }
  }
  #pragma unroll
  for (int o = 32; o; o >>= 1) {
    float ov = __shfl_down(bestv, o); int oi = __shfl_down(besti, o);
    if (ov > bestv || (ov == bestv && oi < besti)) { bestv = ov; besti = oi; }
  }
  if (lane == 0) { sm.redf[wv] = bestv; sm.redi[wv] = besti; }
  __syncthreads();
  if (tid == 0) {
    float bv = sm.redf[0]; int bi = sm.redi[0];
    for (int w = 1; w < NWAVES; w++) {
      if (sm.redf[w] > bv || (sm.redf[w] == bv && sm.redi[w] < bi)) { bv = sm.redf[w]; bi = sm.redi[w]; }
    }
    int sampled = (t < EPSV) ? sm.greedy : bi;
    float ls = lrow[sampled];
    float token_lp = (ls - m) - sm.L;
    sm.token_lp = token_lp;

    float* out_ids = out;
    float* out_idx = out + B;
    float* out_lp  = out + B + (size_t)B * (1 + nlp);
    size_t rb = (size_t)row * (1 + nlp);
    out_ids[row] = (float)sampled;
    out_idx[rb] = (float)sampled;
    out_lp[rb] = token_lp;
    for (int j = 0; j < nlp; j++) {
      uint64_t cd = sm.cand[j];
      int idxj = (int)(uint32_t)(cd & 0xffffffffu);
      float lj = fromOrd(~(uint32_t)(cd >> 32));
      out_idx[rb + 1 + j] = (float)idxj;
      out_lp[rb + 1 + j] = (lj - m) - sm.L;
    }
  }
  __syncthreads();

  // ---- scan 4: token rank = #{ raw_lp_j >= token_lp } ----
  const float Lc = sm.L;
  const float tlp = sm.token_lp;
  int cnt = 0;
  for (int i = tid; i < V4; i += BLOCK) {
    float4 v = l4[i];
    float a[4] = {v.x, v.y, v.z, v.w};
    #pragma unroll
    for (int c = 0; c < 4; c++) {
      float lp = (a[c] - m) - Lc;
      cnt += (lp >= tlp) ? 1 : 0;
    }
  }
  for (int i = Vt + tid; i < V; i += BLOCK) {
    float lp = (lrow[i] - m) - Lc;
    cnt += (lp >= tlp) ? 1 : 0;
  }
  #pragma unroll
  for (int o = 32; o; o >>= 1) cnt += __shfl_down(cnt, o);
  if (lane == 0) sm.redi[wv] = cnt;
  __syncthreads();
  if (tid == 0) {
    int r = 0;
    for (int w = 0; w < NWAVES; w++) r += sm.redi[w];
    out[B + 2 * (size_t)B * (1 + nlp) + row] = (float)r;
  }
}

extern "C" void kernel_launch(void* const* d_in, const int* in_sizes, int n_in,
                              void* d_out, int out_size, void* d_ws, size_t ws_size,
                              hipStream_t stream) {
  const float* logits = (const float*)d_in[0];
  const float* temp   = (const float*)d_in[1];
  const float* minp   = (const float*)d_in[2];
  const float* topp   = (const float*)d_in[3];
  const int*   topk   = (const int*)d_in[4];
  const float* noise  = (const float*)d_in[5];
  int B = in_sizes[1];
  int V = in_sizes[0] / B;
  int nlp = (out_size / B - 4) / 2;
  if (nlp < 0) nlp = 0;
  hipLaunchKernelGGL(sampler_kernel, dim3(B), dim3(BLOCK), 0, stream,
                     logits, temp, minp, topp, topk, noise,
                     (float*)d_out, B, V, nlp);
}

// Round 3
// 251.650 us; speedup vs baseline: 1.6531x; 1.6531x over previous
//
#include <hip/hip_runtime.h>
#include <stdint.h>
#include <math.h>

#define NS 4
#define NBINS 8192
#define CANDC 1024
#define CAND_MIN 128
#define NEGV -1e30f
#define EPSV 1e-5f

__device__ __forceinline__ uint32_t toOrd(float f) {
  uint32_t u = __float_as_uint(f);
  return (u & 0x80000000u) ? ~u : (u | 0x80000000u);
}
__device__ __forceinline__ float fromOrd(uint32_t o) {
  uint32_t u = (o & 0x80000000u) ? (o & 0x7fffffffu) : ~o;
  return __uint_as_float(u);
}

// ---------------- K1: per-(row,chunk) max + histogram ----------------
__global__ void __launch_bounds__(1024)
k1_hist_max(const float* __restrict__ logits, uint32_t* __restrict__ hist,
            float* __restrict__ pmax, int V)
{
  const int chunk = blockIdx.x, row = blockIdx.y;
  const int tid = threadIdx.x, lane = tid & 63, wv = tid >> 6;
  __shared__ uint32_t h[NBINS];
  __shared__ float red[16];
  for (int i = tid; i < NBINS; i += 1024) h[i] = 0u;
  __syncthreads();
  const float* lrow = logits + (size_t)row * V;
  const int clen = ((V + NS - 1) / NS + 3) & ~3;
  const int start = chunk * clen;
  int end = start + clen; if (end > V) end = V;
  float lmax = -INFINITY;
  if (start < end) {
    const int n4 = (end - start) >> 2;
    const float4* p4 = (const float4*)(lrow + start);
    for (int i = tid; i < n4; i += 1024) {
      float4 v = p4[i];
      float a[4] = {v.x, v.y, v.z, v.w};
      #pragma unroll
      for (int c = 0; c < 4; c++) {
        lmax = fmaxf(lmax, a[c]);
        atomicAdd(&h[toOrd(a[c]) >> 19], 1u);
      }
    }
    for (int i = start + (n4 << 2) + tid; i < end; i += 1024) {
      float a = lrow[i];
      lmax = fmaxf(lmax, a);
      atomicAdd(&h[toOrd(a) >> 19], 1u);
    }
  }
  #pragma unroll
  for (int o = 32; o; o >>= 1) lmax = fmaxf(lmax, __shfl_down(lmax, o));
  if (lane == 0) red[wv] = lmax;
  __syncthreads();
  if (tid == 0) {
    float mm = red[0];
    for (int w = 1; w < 16; w++) mm = fmaxf(mm, red[w]);
    pmax[row * NS + chunk] = mm;
  }
  uint32_t* grow = hist + (size_t)row * NBINS;
  for (int i = tid; i < NBINS; i += 1024) {
    uint32_t v = h[i];
    if (v) atomicAdd(&grow[i], v);
  }
}

// ---------------- K2: reduce max, find bstar from global hist ----------------
__global__ void __launch_bounds__(1024)
k2_bstar(const uint32_t* __restrict__ hist, const float* __restrict__ pmax,
         float* __restrict__ m_out, int* __restrict__ bstar_out)
{
  const int row = blockIdx.x, tid = threadIdx.x;
  __shared__ uint32_t sfx[1025];
  __shared__ int gsel;
  const uint32_t* grow = hist + (size_t)row * NBINS;
  const uint4* g4 = (const uint4*)grow;
  uint4 aa = g4[2 * tid], bb = g4[2 * tid + 1];
  uint32_t g = aa.x + aa.y + aa.z + aa.w + bb.x + bb.y + bb.z + bb.w;
  if (tid == 0) { gsel = 0; sfx[1024] = 0; }
  sfx[tid] = g;
  __syncthreads();
  for (int off = 1; off < 1024; off <<= 1) {
    uint32_t v = (tid + off < 1024) ? sfx[tid + off] : 0u;
    __syncthreads();
    sfx[tid] += v;
    __syncthreads();
  }
  uint32_t gs = sfx[tid], gn = sfx[tid + 1];
  if (gs >= CAND_MIN && gn < CAND_MIN) gsel = tid;
  __syncthreads();
  if (tid == 0) {
    int gsl = gsel;
    uint32_t cum = sfx[gsl + 1];
    int bsel = gsl * 8;
    for (int b = gsl * 8 + 7; b >= gsl * 8; b--) {
      cum += grow[b];
      if (cum >= CAND_MIN) { bsel = b; break; }
    }
    bstar_out[row] = bsel;
    float mm = pmax[row * NS + 0];
    for (int c = 1; c < NS; c++) mm = fmaxf(mm, pmax[row * NS + c]);
    m_out[row] = mm;
  }
}

// ---------------- K3: S/Sx partial sums (exact m) + candidate collect ----------------
__global__ void __launch_bounds__(1024)
k3_sums(const float* __restrict__ logits, const float* __restrict__ temp_,
        const float* __restrict__ m_arr, const int* __restrict__ bstar_arr,
        float* __restrict__ pS, float* __restrict__ pSx,
        uint32_t* __restrict__ ccnt, uint64_t* __restrict__ cand, int V)
{
  const int chunk = blockIdx.x, row = blockIdx.y;
  const int tid = threadIdx.x, lane = tid & 63, wv = tid >> 6;
  __shared__ float redS[16], redSx[16];
  const float m = m_arr[row];
  const int bstar = bstar_arr[row];
  const float t = temp_[row];
  const float safe_t = (t < EPSV) ? 1.0f : t;
  const float m_x = m / safe_t;
  const float* lrow = logits + (size_t)row * V;
  const int clen = ((V + NS - 1) / NS + 3) & ~3;
  const int start = chunk * clen;
  int end = start + clen; if (end > V) end = V;
  float S = 0.f, Sx = 0.f;
  if (start < end) {
    const int n4 = (end - start) >> 2;
    const float4* p4 = (const float4*)(lrow + start);
    for (int i = tid; i < n4; i += 1024) {
      float4 v = p4[i];
      float a[4] = {v.x, v.y, v.z, v.w};
      #pragma unroll
      for (int c = 0; c < 4; c++) {
        S += expf(a[c] - m);
        float x = a[c] / safe_t;
        Sx += expf(x - m_x);
        uint32_t o = toOrd(a[c]);
        if ((int)(o >> 19) >= bstar) {
          uint32_t slot = atomicAdd(&ccnt[row], 1u);
          if (slot < CANDC)
            cand[(size_t)row * CANDC + slot] =
                ((uint64_t)(~o) << 32) | (uint32_t)(start + i * 4 + c);
        }
      }
    }
    for (int i = start + (n4 << 2) + tid; i < end; i += 1024) {
      float a = lrow[i];
      S += expf(a - m);
      float x = a / safe_t;
      Sx += expf(x - m_x);
      uint32_t o = toOrd(a);
      if ((int)(o >> 19) >= bstar) {
        uint32_t slot = atomicAdd(&ccnt[row], 1u);
        if (slot < CANDC)
          cand[(size_t)row * CANDC + slot] = ((uint64_t)(~o) << 32) | (uint32_t)i;
      }
    }
  }
  #pragma unroll
  for (int o = 32; o; o >>= 1) { S += __shfl_down(S, o); Sx += __shfl_down(Sx, o); }
  if (lane == 0) { redS[wv] = S; redSx[wv] = Sx; }
  __syncthreads();
  if (tid == 0) {
    float s = 0, sx = 0;
    for (int w = 0; w < 16; w++) { s += redS[w]; sx += redSx[w]; }
    pS[row * NS + chunk] = s;
    pSx[row * NS + chunk] = sx;
  }
}

// ---------------- K4: sort candidates, cutoffs, gumbel argmax, rank, outputs ----------------
__global__ void __launch_bounds__(1024)
k4_final(const float* __restrict__ temp_, const float* __restrict__ minp_,
         const float* __restrict__ topp_, const int* __restrict__ topk_,
         const float* __restrict__ noise_,
         const float* __restrict__ m_arr, const float* __restrict__ pS,
         const float* __restrict__ pSx, const uint32_t* __restrict__ ccnt,
         const uint64_t* __restrict__ candG, float* __restrict__ out,
         int B, int V, int nlp)
{
  const int row = blockIdx.x, tid = threadIdx.x, lane = tid & 63, wv = tid >> 6;
  __shared__ uint64_t cd[CANDC];
  __shared__ float redv[16], redl[16];
  __shared__ int redi[16], redr[16];
  __shared__ float sh_kth, sh_cut, sh_mpthr, sh_m, sh_L, sh_safe_t, sh_mx, sh_Sx, sh_tlp;
  __shared__ int sh_count;
  int count = (int)ccnt[row]; if (count > CANDC) count = CANDC;
  cd[tid] = (tid < count) ? candG[(size_t)row * CANDC + tid] : ~0ull;
  if (tid == 0) sh_count = count;
  __syncthreads();
  // bitonic sort ascending on key (~ord<<32 | idx) => value desc, idx asc
  for (int ks = 2; ks <= CANDC; ks <<= 1) {
    for (int j = ks >> 1; j; j >>= 1) {
      int p = tid ^ j;
      if (p > tid) {
        uint64_t a = cd[tid], b = cd[p];
        bool up = ((tid & ks) == 0);
        if ((a > b) == up) { cd[tid] = b; cd[p] = a; }
      }
      __syncthreads();
    }
  }
  if (tid == 0) {
    float S = 0, Sx = 0;
    for (int c = 0; c < NS; c++) { S += pS[row * NS + c]; Sx += pSx[row * NS + c]; }
    float m = m_arr[row];
    float L = logf(S);
    float t = temp_[row];
    float safe_t = (t < EPSV) ? 1.0f : t;
    float m_x = m / safe_t;
    int i64mode = (B > 1 && topk_[1] == 0) ? 1 : 0;
    int kraw = i64mode ? topk_[2 * row] : topk_[row];
    int k = kraw < 1 ? 1 : (kraw > V ? V : kraw);
    int keff = k < count ? k : count;
    float mpthr = minp_[row] * (1.0f / Sx);
    float topp = topp_[row];
    int np = 0;
    while (np < keff) {
      float xl = fromOrd(~(uint32_t)(cd[np] >> 32)) / safe_t;
      float p = expf(xl - m_x) / Sx;
      if (p < mpthr) break;
      np++;
    }
    float kth_x = NEGV;
    if (np == k) kth_x = fromOrd(~(uint32_t)(cd[k - 1] >> 32)) / safe_t;
    int kk = np;
    float S2 = 0.f;
    for (int i = 0; i < kk; i++)
      S2 += expf(fromOrd(~(uint32_t)(cd[i] >> 32)) / safe_t - m_x);
    float cum = 0.f; int nkeep = 0;
    for (int i = 0; i < kk; i++) {
      float xl = fromOrd(~(uint32_t)(cd[i] >> 32)) / safe_t;
      float sp = expf(xl - m_x) / S2;
      cum += sp;
      if (cum - sp < topp) nkeep++;
    }
    float cutoff_x = NEGV;
    if (!(cum < topp)) {
      if (nkeep < 1) nkeep = 1;
      cutoff_x = fromOrd(~(uint32_t)(cd[nkeep - 1] >> 32)) / safe_t;
    }
    sh_kth = kth_x; sh_cut = cutoff_x; sh_mpthr = mpthr; sh_m = m; sh_L = L;
    sh_safe_t = safe_t; sh_mx = m_x; sh_Sx = Sx;
  }
  __syncthreads();
  // gumbel argmax over kept candidates (scattered noise reads)
  float bestv = -INFINITY, bestl = 0.f; int besti = 0x7fffffff;
  if (tid < sh_count) {
    uint64_t c = cd[tid];
    float l = fromOrd(~(uint32_t)(c >> 32));
    int idx = (int)(uint32_t)(c & 0xffffffffu);
    float x = l / sh_safe_t;
    float p = expf(x - sh_mx) / sh_Sx;
    if (p >= sh_mpthr && x >= sh_kth && x >= sh_cut) {
      float u = noise_[(size_t)row * V + idx];
      bestv = x + (-logf(-logf(u)));
      besti = idx; bestl = l;
    }
  }
  #pragma unroll
  for (int o = 32; o; o >>= 1) {
    float ov = __shfl_down(bestv, o); int oi = __shfl_down(besti, o); float ol = __shfl_down(bestl, o);
    if (ov > bestv || (ov == bestv && oi < besti)) { bestv = ov; besti = oi; bestl = ol; }
  }
  if (lane == 0) { redv[wv] = bestv; redi[wv] = besti; redl[wv] = bestl; }
  __syncthreads();
  if (tid == 0) {
    float bv = redv[0]; int bi = redi[0]; float bl = redl[0];
    for (int w = 1; w < 16; w++) {
      if (redv[w] > bv || (redv[w] == bv && redi[w] < bi)) { bv = redv[w]; bi = redi[w]; bl = redl[w]; }
    }
    float t = temp_[row];
    int sampled; float ls;
    if (t < EPSV) {
      uint64_t c0 = cd[0];
      sampled = (int)(uint32_t)(c0 & 0xffffffffu);
      ls = fromOrd(~(uint32_t)(c0 >> 32));
    } else { sampled = bi; ls = bl; }
    float token_lp = (ls - sh_m) - sh_L;
    sh_tlp = token_lp;
    float* out_idx = out + B;
    float* out_lp = out + B + (size_t)B * (1 + nlp);
    size_t rb = (size_t)row * (1 + nlp);
    out[row] = (float)sampled;
    out_idx[rb] = (float)sampled;
    out_lp[rb] = token_lp;
    for (int j = 0; j < nlp; j++) {
      uint64_t c = cd[j];
      out_idx[rb + 1 + j] = (float)(int)(uint32_t)(c & 0xffffffffu);
      out_lp[rb + 1 + j] = (fromOrd(~(uint32_t)(c >> 32)) - sh_m) - sh_L;
    }
  }
  __syncthreads();
  // rank: count over candidates (non-candidates can't reach token_lp; gap >> ulp)
  int cnt = 0;
  if (tid < sh_count) {
    float l = fromOrd(~(uint32_t)(cd[tid] >> 32));
    float f = (l - sh_m) - sh_L;
    cnt = (f >= sh_tlp) ? 1 : 0;
  }
  #pragma unroll
  for (int o = 32; o; o >>= 1) cnt += __shfl_down(cnt, o);
  if (lane == 0) redr[wv] = cnt;
  __syncthreads();
  if (tid == 0) {
    int r = 0;
    for (int w = 0; w < 16; w++) r += redr[w];
    out[B + 2 * (size_t)B * (1 + nlp) + row] = (float)r;
  }
}

// ================= fallback: proven monolithic kernel (R2, passed) =================
#define FB_BLOCK 1024
#define FB_CAP 2048
#define FB_NW 16

struct FBSM {
  uint32_t hist[NBINS];
  uint64_t cand[FB_CAP];
  float redf[FB_NW];
  int   redi[FB_NW];
  int cnt; int bstar;
  float m, S, Sx;
  float kth_x, cutoff_x, mpthr;
  float L, token_lp;
  int greedy;
};

__device__ __forceinline__ float fbCandVal(const uint64_t* cand, int i) {
  return fromOrd(~(uint32_t)(cand[i] >> 32));
}

__global__ void __launch_bounds__(FB_BLOCK)
sampler_fallback(const float* __restrict__ logits, const float* __restrict__ temp_,
                 const float* __restrict__ minp_, const float* __restrict__ topp_,
                 const int* __restrict__ topk_, const float* __restrict__ noise_,
                 float* __restrict__ out, int B, int V, int nlp)
{
  __shared__ FBSM sm;
  const int row = blockIdx.x, tid = threadIdx.x, lane = tid & 63, wv = tid >> 6;
  const float* lrow = logits + (size_t)row * V;
  const float* nrow = noise_ + (size_t)row * V;
  const int V4 = V >> 2, Vt = V4 << 2;
  const float4* l4 = (const float4*)lrow;
  const float4* n4 = (const float4*)nrow;
  for (int i = tid; i < NBINS; i += FB_BLOCK) sm.hist[i] = 0u;
  if (tid == 0) sm.cnt = 0;
  __syncthreads();
  float lmax = -INFINITY;
  for (int i = tid; i < V4; i += FB_BLOCK) {
    float4 v = l4[i]; float a[4] = {v.x, v.y, v.z, v.w};
    #pragma unroll
    for (int c = 0; c < 4; c++) { lmax = fmaxf(lmax, a[c]); atomicAdd(&sm.hist[toOrd(a[c]) >> 19], 1u); }
  }
  for (int i = Vt + tid; i < V; i += FB_BLOCK) {
    float a = lrow[i]; lmax = fmaxf(lmax, a); atomicAdd(&sm.hist[toOrd(a) >> 19], 1u);
  }
  #pragma unroll
  for (int o = 32; o; o >>= 1) lmax = fmaxf(lmax, __shfl_down(lmax, o));
  if (lane == 0) sm.redf[wv] = lmax;
  __syncthreads();
  if (tid == 0) {
    float mm = sm.redf[0];
    for (int w = 1; w < FB_NW; w++) mm = fmaxf(mm, sm.redf[w]);
    sm.m = mm;
    uint32_t cum = 0; int b = NBINS - 1;
    for (; b > 0; b--) { cum += sm.hist[b]; if (cum >= CAND_MIN) break; }
    sm.bstar = b;
  }
  __syncthreads();
  const float m = sm.m;
  const int bstar = sm.bstar;
  const float t = temp_[row];
  const float safe_t = (t < EPSV) ? 1.0f : t;
  const float m_x = m / safe_t;
  float S = 0.f, Sx = 0.f;
  for (int i = tid; i < V4; i += FB_BLOCK) {
    float4 v = l4[i]; float a[4] = {v.x, v.y, v.z, v.w};
    #pragma unroll
    for (int c = 0; c < 4; c++) {
      S += expf(a[c] - m);
      float x = a[c] / safe_t; Sx += expf(x - m_x);
      uint32_t o = toOrd(a[c]);
      if ((int)(o >> 19) >= bstar) {
        int slot = atomicAdd(&sm.cnt, 1);
        if (slot < FB_CAP) sm.cand[slot] = ((uint64_t)(~o) << 32) | (uint32_t)(i * 4 + c);
      }
    }
  }
  for (int i = Vt + tid; i < V; i += FB_BLOCK) {
    float a = lrow[i];
    S += expf(a - m);
    float x = a / safe_t; Sx += expf(x - m_x);
    uint32_t o = toOrd(a);
    if ((int)(o >> 19) >= bstar) {
      int slot = atomicAdd(&sm.cnt, 1);
      if (slot < FB_CAP) sm.cand[slot] = ((uint64_t)(~o) << 32) | (uint32_t)i;
    }
  }
  #pragma unroll
  for (int o = 32; o; o >>= 1) { S += __shfl_down(S, o); Sx += __shfl_down(Sx, o); }
  if (lane == 0) sm.redf[wv] = S;
  __syncthreads();
  if (tid == 0) { float s = 0; for (int w = 0; w < FB_NW; w++) s += sm.redf[w]; sm.S = s; }
  __syncthreads();
  if (lane == 0) sm.redf[wv] = Sx;
  __syncthreads();
  if (tid == 0) { float s = 0; for (int w = 0; w < FB_NW; w++) s += sm.redf[w]; sm.Sx = s; }
  __syncthreads();
  const int count = min(sm.cnt, FB_CAP);
  for (int i = count + tid; i < FB_CAP; i += FB_BLOCK) sm.cand[i] = ~0ull;
  __syncthreads();
  for (int ks = 2; ks <= FB_CAP; ks <<= 1) {
    for (int j = ks >> 1; j > 0; j >>= 1) {
      for (int e = tid; e < FB_CAP; e += FB_BLOCK) {
        int p = e ^ j;
        if (p > e) {
          uint64_t a = sm.cand[e], b2 = sm.cand[p];
          bool up = ((e & ks) == 0);
          if ((a > b2) == up) { sm.cand[e] = b2; sm.cand[p] = a; }
        }
      }
      __syncthreads();
    }
  }
  if (tid == 0) {
    const float Sx_ = sm.Sx;
    const float L = logf(sm.S);
    sm.L = L;
    int i64mode = (B > 1 && topk_[1] == 0) ? 1 : 0;
    int kraw = i64mode ? topk_[2 * row] : topk_[row];
    int k = kraw < 1 ? 1 : (kraw > V ? V : kraw);
    int keff = k < count ? k : count;
    float mpthr = minp_[row] * (1.0f / Sx_);
    sm.mpthr = mpthr;
    float topp = topp_[row];
    int np = 0;
    while (np < keff) {
      float xl = fbCandVal(sm.cand, np) / safe_t;
      float p = expf(xl - m_x) / Sx_;
      if (p < mpthr) break;
      np++;
    }
    float kth_x = NEGV;
    if (np == k) kth_x = fbCandVal(sm.cand, k - 1) / safe_t;
    int kk = np;
    float S2 = 0.f;
    for (int i = 0; i < kk; i++) S2 += expf(fbCandVal(sm.cand, i) / safe_t - m_x);
    float cum = 0.f; int nkeep = 0;
    for (int i = 0; i < kk; i++) {
      float xl = fbCandVal(sm.cand, i) / safe_t;
      float sp = expf(xl - m_x) / S2;
      cum += sp;
      if (cum - sp < topp) nkeep++;
    }
    float cutoff_x = NEGV;
    if (!(cum < topp)) { if (nkeep < 1) nkeep = 1; cutoff_x = fbCandVal(sm.cand, nkeep - 1) / safe_t; }
    sm.kth_x = kth_x; sm.cutoff_x = cutoff_x;
    sm.greedy = (int)(uint32_t)(sm.cand[0] & 0xffffffffu);
  }
  __syncthreads();
  const float kth_x = sm.kth_x, cutoff_x = sm.cutoff_x, mpthr = sm.mpthr, SxR = sm.Sx;
  float bestv = -INFINITY; int besti = 0;
  for (int i = tid; i < V4; i += FB_BLOCK) {
    float4 lv = l4[i]; float4 uv = n4[i];
    float la[4] = {lv.x, lv.y, lv.z, lv.w};
    float ua[4] = {uv.x, uv.y, uv.z, uv.w};
    #pragma unroll
    for (int c = 0; c < 4; c++) {
      float x = la[c] / safe_t;
      float p = expf(x - m_x) / SxR;
      float val = NEGV;
      if (p >= mpthr && x >= kth_x && x >= cutoff_x) val = x + (-logf(-logf(ua[c])));
      if (val > bestv) { bestv = val; besti = i * 4 + c; }
    }
  }
  for (int i = Vt + tid; i < V; i += FB_BLOCK) {
    float x = lrow[i] / safe_t;
    float p = expf(x - m_x) / SxR;
    float val = NEGV;
    if (p >= mpthr && x >= kth_x && x >= cutoff_x) val = x + (-logf(-logf(nrow[i])));
    if (val > bestv) { bestv = val; besti = i; }
  }
  #pragma unroll
  for (int o = 32; o; o >>= 1) {
    float ov = __shfl_down(bestv, o); int oi = __shfl_down(besti, o);
    if (ov > bestv || (ov == bestv && oi < besti)) { bestv = ov; besti = oi; }
  }
  if (lane == 0) { sm.redf[wv] = bestv; sm.redi[wv] = besti; }
  __syncthreads();
  if (tid == 0) {
    float bv = sm.redf[0]; int bi = sm.redi[0];
    for (int w = 1; w < FB_NW; w++) {
      if (sm.redf[w] > bv || (sm.redf[w] == bv && sm.redi[w] < bi)) { bv = sm.redf[w]; bi = sm.redi[w]; }
    }
    int sampled = (t < EPSV) ? sm.greedy : bi;
    float ls = lrow[sampled];
    float token_lp = (ls - m) - sm.L;
    sm.token_lp = token_lp;
    float* out_idx = out + B;
    float* out_lp = out + B + (size_t)B * (1 + nlp);
    size_t rb = (size_t)row * (1 + nlp);
    out[row] = (float)sampled;
    out_idx[rb] = (float)sampled;
    out_lp[rb] = token_lp;
    for (int j = 0; j < nlp; j++) {
      uint64_t cdv = sm.cand[j];
      out_idx[rb + 1 + j] = (float)(int)(uint32_t)(cdv & 0xffffffffu);
      out_lp[rb + 1 + j] = (fromOrd(~(uint32_t)(cdv >> 32)) - m) - sm.L;
    }
  }
  __syncthreads();
  const float Lc = sm.L, tlp = sm.token_lp;
  int cnt = 0;
  for (int i = tid; i < V4; i += FB_BLOCK) {
    float4 v = l4[i]; float a[4] = {v.x, v.y, v.z, v.w};
    #pragma unroll
    for (int c = 0; c < 4; c++) { float lp = (a[c] - m) - Lc; cnt += (lp >= tlp) ? 1 : 0; }
  }
  for (int i = Vt + tid; i < V; i += FB_BLOCK) {
    float lp = (lrow[i] - m) - Lc; cnt += (lp >= tlp) ? 1 : 0;
  }
  #pragma unroll
  for (int o = 32; o; o >>= 1) cnt += __shfl_down(cnt, o);
  if (lane == 0) sm.redi[wv] = cnt;
  __syncthreads();
  if (tid == 0) {
    int r = 0;
    for (int w = 0; w < FB_NW; w++) r += sm.redi[w];
    out[B + 2 * (size_t)B * (1 + nlp) + row] = (float)r;
  }
}

extern "C" void kernel_launch(void* const* d_in, const int* in_sizes, int n_in,
                              void* d_out, int out_size, void* d_ws, size_t ws_size,
                              hipStream_t stream) {
  const float* logits = (const float*)d_in[0];
  const float* temp   = (const float*)d_in[1];
  const float* minp   = (const float*)d_in[2];
  const float* topp   = (const float*)d_in[3];
  const int*   topk   = (const int*)d_in[4];
  const float* noise  = (const float*)d_in[5];
  int B = in_sizes[1];
  int V = in_sizes[0] / B;
  int nlp = (out_size / B - 4) / 2;
  if (nlp < 0) nlp = 0;

  uint8_t* ws = (uint8_t*)d_ws;
  size_t off = 0;
  uint32_t* hist = (uint32_t*)(ws + off); off += (size_t)B * NBINS * 4;
  uint32_t* ccnt = (uint32_t*)(ws + off); off += (size_t)B * 4;
  size_t zeroBytes = off;
  float* pmax = (float*)(ws + off); off += (size_t)B * NS * 4;
  float* pS   = (float*)(ws + off); off += (size_t)B * NS * 4;
  float* pSx  = (float*)(ws + off); off += (size_t)B * NS * 4;
  float* m_arr = (float*)(ws + off); off += (size_t)B * 4;
  int* bstar  = (int*)(ws + off); off += (size_t)B * 4;
  off = (off + 7) & ~(size_t)7;
  uint64_t* cand = (uint64_t*)(ws + off); off += (size_t)B * CANDC * 8;

  if (ws_size < off) {
    hipLaunchKernelGGL(sampler_fallback, dim3(B), dim3(FB_BLOCK), 0, stream,
                       logits, temp, minp, topp, topk, noise, (float*)d_out, B, V, nlp);
    return;
  }

  hipMemsetAsync(d_ws, 0, zeroBytes, stream);
  hipLaunchKernelGGL(k1_hist_max, dim3(NS, B), dim3(1024), 0, stream, logits, hist, pmax, V);
  hipLaunchKernelGGL(k2_bstar, dim3(B), dim3(1024), 0, stream, hist, pmax, m_arr, bstar);
  hipLaunchKernelGGL(k3_sums, dim3(NS, B), dim3(1024), 0, stream,
                     logits, temp, m_arr, bstar, pS, pSx, ccnt, cand, V);
  hipLaunchKernelGGL(k4_final, dim3(B), dim3(1024), 0, stream,
                     temp, minp, topp, topk, noise, m_arr, pS, pSx, ccnt, cand,
                     (float*)d_out, B, V, nlp);
}